// Round 7
// baseline (85.629 us; speedup 1.0000x reference)
//
#include <hip/hip_runtime.h>
#include <math.h>

#define HDIM 512
#define NH   32
#define LTOT 8192
#define CHUNK 8     // consecutive l per thread (4 packed pairs)
#define TPB  256
#define BANDL  512  // l per wave-band; 16 bands per h
#define WS_BYTES (HDIM * 96 * 16)  // 512 h x 96 float4 = 768 KB

typedef float v2f __attribute__((ext_vector_type(2)));

// Round 7: TWO-KERNEL SPLIT. Bottom-up accounting says main loop ~3us, write
// ~1us, overhead ~1.4us, yet K=13.4us. The constant across all null rounds is
// the per-block prologue: serial ocml expf/sincosf chain replicated in 2048
// blocks + its register-pressure tax on the whole kernel. Kernel A computes
// per-(h,n) params ONCE (16K threads, sorted by decay rate within each h via
// 32-lane shuffle rank sort) into d_ws; kernel B's prologue becomes 96
// coalesced float4 loads -> LDS (no libm, low VGPR -> real 8 waves/SIMD).

__device__ __forceinline__ void compute_params(
    int h, int n, const float* log_dt, const float* log_A_real,
    const float* A_imag, const float* Bmat, const float* Cmat,
    float4& P0, float4& P1, float4& P2, float& key)
{
    const int idx = h * NH + n;
    const float dt = expf(log_dt[h]);
    const float Ar = -expf(log_A_real[idx]);   // A = -exp(lar) - i*A_imag
    const float Ai = -A_imag[idx];
    const float re = Ar * dt;                  // dtA (re < 0)
    const float im = Ai * dt;
    float sw, cw;
    sincosf(im, &sw, &cw);                     // precise: small arg
    const float er = expf(re);
    const float wr = er * cw;                  // w = exp(dtA)
    const float wi = er * sw;
    // (w - 1) / A
    const float inv = 1.0f / (Ar * Ar + Ai * Ai);
    const float nr = wr - 1.0f, ni = wi;
    const float qr = (nr * Ar + ni * Ai) * inv;
    const float qi = (ni * Ar - nr * Ai) * inv;
    // E0 = 2 * Bc * Cc * (w-1)/A
    const float Br = Bmat[2 * idx], Bi = Bmat[2 * idx + 1];
    const float Cr = Cmat[2 * idx], Ci = Cmat[2 * idx + 1];
    const float bcr = Br * Cr - Bi * Ci;
    const float bci = Br * Ci + Bi * Cr;
    const float e0r = 2.0f * (bcr * qr - bci * qi);
    const float e0i = 2.0f * (bcr * qi + bci * qr);
    // Ej = E0 * w^j
    const float e1r = e0r * wr - e0i * wi, e1i = e0r * wi + e0i * wr;
    const float e2r = e1r * wr - e1i * wi, e2i = e1r * wi + e1i * wr;
    const float e3r = e2r * wr - e2i * wi, e3i = e2r * wi + e2i * wr;
    const float b1 = er * er;                  // |w|^2
    key = re * 1.44269504089f;                 // log2-domain decay rate (<0)
    P0 = make_float4(key, im * 0.15915494309f,
                     2.0f * (wr * wr - wi * wi), b1 * b1);
    P1 = make_float4(e0r, e1r, e0i, e1i);
    P2 = make_float4(e2r, e3r, e2i, e3i);
}

// Kernel A: 64 blocks x 256 threads = one thread per (h,n).
__global__ __launch_bounds__(TPB) void s4_params(
    const float* __restrict__ log_dt,
    const float* __restrict__ log_A_real,
    const float* __restrict__ A_imag,
    const float* __restrict__ Bmat,
    const float* __restrict__ Cmat,
    float4* __restrict__ ws)
{
    const int idx = blockIdx.x * TPB + threadIdx.x;  // 0..16383
    const int h = idx >> 5;
    const int n = idx & 31;
    float4 P0, P1, P2;
    float key;
    compute_params(h, n, log_dt, log_A_real, A_imag, Bmat, Cmat,
                   P0, P1, P2, key);
    // Rank-sort within the 32-lane h-group, slowest decay (key closest to 0)
    // first. Distinct random keys; lane-index tiebreak for determinism.
    int rank = 0;
#pragma unroll
    for (int m = 0; m < 32; ++m) {
        const float km = __shfl(key, m, 32);
        rank += (km > key || (km == key && m < n)) ? 1 : 0;
    }
    float4* base = ws + h * 96;
    base[rank]      = P0;
    base[32 + rank] = P1;
    base[64 + rank] = P2;
}

// Kernel B: main evaluation; prologue = 96 coalesced float4 loads.
__global__ __launch_bounds__(TPB, 8) void s4_main(
    const float4* __restrict__ ws,
    float* __restrict__ out)
{
    __shared__ float4 sp[96];   // [0:32)=p0, [32:64)=p1, [64:96)=p2 (sorted)

    const int bid  = blockIdx.x;
    const int h    = bid & (HDIM - 1);   // q-major: bid = q*HDIM + h
    const int q    = bid >> 9;
    const int tid  = threadIdx.x;

    if (tid < 96) sp[tid] = ws[h * 96 + tid];
    __syncthreads();

    const int wave = tid >> 6;
    const int lane = tid & 63;
    const int band = wave * 4 + q;               // stride-4 decay sampling
    const int l0   = band * BANDL + lane * CHUNK;
    const float l0f    = (float)l0;
    const float l0minf = (float)(band * BANDL);  // wave-uniform min l

    v2f acc2[CHUNK / 2];
#pragma unroll
    for (int k = 0; k < CHUNK / 2; ++k) acc2[k] = v2f{0.0f, 0.0f};

#pragma unroll 1
    for (int n = 0; n < NH; ++n) {
        const float4 P0 = sp[n];
        // Sorted by decay: first pole dead at this wave's min l => all later
        // poles dead too.
        if (P0.x * l0minf < -17.3f) break;     // 2^-17.3 ~ 6e-6
        const float4 Q1 = sp[32 + n];
        const float4 Q2 = sp[64 + n];
        float ph = P0.y * l0f;                 // phase in revolutions
        ph = __builtin_amdgcn_fractf(ph);
        const float s = __builtin_amdgcn_sinf(ph);   // sin(2*pi*ph)
        const float c = __builtin_amdgcn_cosf(ph);
        const float e = __builtin_amdgcn_exp2f(P0.x * l0f); // ->0 past cut
        const float kr = e * c;                // K(l0) = exp(dtA*l0)
        const float ki = e * s;
        // seeds: Pa = (u0,u1), Pb = (u2,u3);  u_j = Re(Ej * K)
        v2f Pa = v2f{Q1.x, Q1.y} * kr - v2f{Q1.z, Q1.w} * ki;
        v2f Pb = v2f{Q2.x, Q2.y} * kr - v2f{Q2.z, Q2.w} * ki;
        acc2[0] += Pa;
        acc2[1] += Pb;
        const v2f a2 = v2f{P0.z, P0.z};
        const v2f b2 = v2f{P0.w, P0.w};
#pragma unroll
        for (int k = 2; k < CHUNK / 2; ++k) {
            const v2f Pn = a2 * Pb - b2 * Pa;  // packed: pk_mul + pk_fma
            acc2[k] += Pn;
            Pa = Pb;
            Pb = Pn;
        }
    }

    float4* o = (float4*)(out + (size_t)h * LTOT + l0);
#pragma unroll
    for (int j = 0; j < CHUNK / 4; ++j)
        o[j] = make_float4(acc2[2 * j].x, acc2[2 * j].y,
                           acc2[2 * j + 1].x, acc2[2 * j + 1].y);
}

// Fallback: monolithic round-6 kernel (used only if ws is too small).
__global__ __launch_bounds__(TPB, 8) void s4_kernel_mono(
    const float* __restrict__ log_dt,
    const float* __restrict__ log_A_real,
    const float* __restrict__ A_imag,
    const float* __restrict__ Bmat,
    const float* __restrict__ Cmat,
    float* __restrict__ out)
{
    __shared__ float4 p0[NH];
    __shared__ float4 p1[NH];
    __shared__ float4 p2[NH];

    const int bid  = blockIdx.x;
    const int h    = bid & (HDIM - 1);
    const int q    = bid >> 9;
    const int tid  = threadIdx.x;

    if (tid < NH) {
        const int n = tid;
        float4 P0, P1, P2;
        float key;
        compute_params(h, n, log_dt, log_A_real, A_imag, Bmat, Cmat,
                       P0, P1, P2, key);
        int rank = 0;
#pragma unroll
        for (int m = 0; m < NH; ++m) {
            const float km = __shfl(key, m, 64);
            rank += (km > key || (km == key && m < n)) ? 1 : 0;
        }
        p0[rank] = P0; p1[rank] = P1; p2[rank] = P2;
    }
    __syncthreads();

    const int wave = tid >> 6;
    const int lane = tid & 63;
    const int band = wave * 4 + q;
    const int l0   = band * BANDL + lane * CHUNK;
    const float l0f    = (float)l0;
    const float l0minf = (float)(band * BANDL);

    v2f acc2[CHUNK / 2];
#pragma unroll
    for (int k = 0; k < CHUNK / 2; ++k) acc2[k] = v2f{0.0f, 0.0f};

#pragma unroll 1
    for (int n = 0; n < NH; ++n) {
        const float4 P0 = p0[n];
        if (P0.x * l0minf < -17.3f) break;
        const float4 Q1 = p1[n];
        const float4 Q2 = p2[n];
        float ph = P0.y * l0f;
        ph = __builtin_amdgcn_fractf(ph);
        const float s = __builtin_amdgcn_sinf(ph);
        const float c = __builtin_amdgcn_cosf(ph);
        const float e = __builtin_amdgcn_exp2f(P0.x * l0f);
        const float kr = e * c;
        const float ki = e * s;
        v2f Pa = v2f{Q1.x, Q1.y} * kr - v2f{Q1.z, Q1.w} * ki;
        v2f Pb = v2f{Q2.x, Q2.y} * kr - v2f{Q2.z, Q2.w} * ki;
        acc2[0] += Pa;
        acc2[1] += Pb;
        const v2f a2 = v2f{P0.z, P0.z};
        const v2f b2 = v2f{P0.w, P0.w};
#pragma unroll
        for (int k = 2; k < CHUNK / 2; ++k) {
            const v2f Pn = a2 * Pb - b2 * Pa;
            acc2[k] += Pn;
            Pa = Pb;
            Pb = Pn;
        }
    }

    float4* o = (float4*)(out + (size_t)h * LTOT + l0);
#pragma unroll
    for (int j = 0; j < CHUNK / 4; ++j)
        o[j] = make_float4(acc2[2 * j].x, acc2[2 * j].y,
                           acc2[2 * j + 1].x, acc2[2 * j + 1].y);
}

extern "C" void kernel_launch(void* const* d_in, const int* in_sizes, int n_in,
                              void* d_out, int out_size, void* d_ws, size_t ws_size,
                              hipStream_t stream)
{
    (void)in_sizes; (void)n_in; (void)out_size;
    const float* log_dt     = (const float*)d_in[0];
    const float* log_A_real = (const float*)d_in[1];
    const float* A_imag     = (const float*)d_in[2];
    const float* Bmat       = (const float*)d_in[3];
    const float* Cmat       = (const float*)d_in[4];
    float* out = (float*)d_out;

    if (d_ws != nullptr && ws_size >= (size_t)WS_BYTES) {
        float4* ws = (float4*)d_ws;
        s4_params<<<dim3(HDIM * NH / TPB), dim3(TPB), 0, stream>>>(
            log_dt, log_A_real, A_imag, Bmat, Cmat, ws);
        s4_main<<<dim3(HDIM * 4), dim3(TPB), 0, stream>>>(ws, out);
    } else {
        s4_kernel_mono<<<dim3(HDIM * 4), dim3(TPB), 0, stream>>>(
            log_dt, log_A_real, A_imag, Bmat, Cmat, out);
    }
}

// Round 8
// 85.408 us; speedup vs baseline: 1.0026x; 1.0026x over previous
//
#include <hip/hip_runtime.h>
#include <math.h>

#define HDIM 512
#define NH   32
#define LTOT 8192
#define TPB  256
#define BANDL 512   // l per wave-band; 16 bands per h

typedef float v2f __attribute__((ext_vector_type(2)));

// Round 8: FULLY-COALESCED STORES (lane-major quad mapping).
// All prior levers (scheduling r1, occupancy r3, balance r4, work r6,
// prologue r7) were null; the invariant across all versions was the store
// pattern: consecutive-l-per-thread puts wave store-lane addresses at
// 32B stride, so no single store instruction fully covers a cache line
// (partial-sector writes -> potential L2 read-merge of the 16MB poisoned
// output every launch). This version assigns each thread two 4-l quads at
// l = Lb + 4*lane (+256): wave stores are lane-contiguous float4 = 1024B
// fully-covered per instruction (same as the RFO-free fill pattern).
// The stride-2 recurrence is gone: seeds E0..E3 produce a quad directly;
// quad1 reuses K(l0) via one complex mul by precomputed w^256.
__global__ __launch_bounds__(TPB, 8) void s4_kernel(
    const float* __restrict__ log_dt,
    const float* __restrict__ log_A_real,
    const float* __restrict__ A_imag,
    const float* __restrict__ Bmat,
    const float* __restrict__ Cmat,
    float* __restrict__ out)
{
    __shared__ float4 p0[NH]; // key=re*log2e, im/(2pi), w256r, w256i
    __shared__ float4 p1[NH]; // E0r, E1r, E0i, E1i   (Ej = 2*Ceff*w^j)
    __shared__ float4 p2[NH]; // E2r, E3r, E2i, E3i

    const int bid  = blockIdx.x;
    const int h    = bid & (HDIM - 1);   // q-major ordering: bid = q*HDIM + h
    const int q    = bid >> 9;
    const int tid  = threadIdx.x;

    if (tid < NH) {
        const int n   = tid;
        const int idx = h * NH + n;
        const float dt = expf(log_dt[h]);
        const float Ar = -expf(log_A_real[idx]);   // A = -exp(lar) - i*A_imag
        const float Ai = -A_imag[idx];
        const float re = Ar * dt;                  // dtA (re < 0)
        const float im = Ai * dt;
        float sw, cw;
        sincosf(im, &sw, &cw);                     // precise: small arg
        const float er = expf(re);
        const float wr = er * cw;                  // w = exp(dtA)
        const float wi = er * sw;
        // (w - 1) / A
        const float inv = 1.0f / (Ar * Ar + Ai * Ai);
        const float nr = wr - 1.0f, ni = wi;
        const float qr = (nr * Ar + ni * Ai) * inv;
        const float qi = (ni * Ar - nr * Ai) * inv;
        // E0 = 2 * Bc * Cc * (w-1)/A
        const float Br = Bmat[2 * idx], Bi = Bmat[2 * idx + 1];
        const float Cr = Cmat[2 * idx], Ci = Cmat[2 * idx + 1];
        const float bcr = Br * Cr - Bi * Ci;
        const float bci = Br * Ci + Bi * Cr;
        const float e0r = 2.0f * (bcr * qr - bci * qi);
        const float e0i = 2.0f * (bcr * qi + bci * qr);
        // Ej = E0 * w^j
        const float e1r = e0r * wr - e0i * wi, e1i = e0r * wi + e0i * wr;
        const float e2r = e1r * wr - e1i * wi, e2i = e1r * wi + e1i * wr;
        const float e3r = e2r * wr - e2i * wi, e3i = e2r * wi + e2i * wr;
        // w^256 = exp(256*dtA), computed directly (exact, no accumulation)
        float s256, c256;
        sincosf(256.0f * im, &s256, &c256);
        const float er256 = expf(256.0f * re);     // underflow -> 0, fine
        const float w256r = er256 * c256;
        const float w256i = er256 * s256;

        // Rank-sort poles by decay rate, slowest (key closest to 0) first.
        const float key = re * 1.44269504089f;
        int rank = 0;
#pragma unroll
        for (int m = 0; m < NH; ++m) {
            const float km = __shfl(key, m, 64);
            rank += (km > key || (km == key && m < n)) ? 1 : 0;
        }
        p0[rank] = make_float4(key, im * 0.15915494309f, w256r, w256i);
        p1[rank] = make_float4(e0r, e1r, e0i, e1i);
        p2[rank] = make_float4(e2r, e3r, e2i, e3i);
    }
    __syncthreads();

    const int wave = tid >> 6;
    const int lane = tid & 63;
    const int band = wave * 4 + q;               // stride-4 decay sampling
    const int Lb   = band * BANDL;
    const int l0   = Lb + lane * 4;              // quad0; quad1 = l0 + 256
    const float l0f = (float)l0;
    const float Lbf = (float)Lb;                 // wave-uniform min l

    // acc[0:2) = quad0 pairs (u0,u1),(u2,u3); acc[2:4) = quad1 pairs
    v2f acc2[4];
#pragma unroll
    for (int k = 0; k < 4; ++k) acc2[k] = v2f{0.0f, 0.0f};

#pragma unroll 1
    for (int n = 0; n < NH; ++n) {
        const float4 P0 = p0[n];
        // Sorted by decay: first pole dead at this wave's min l => all later
        // poles dead too.
        if (P0.x * Lbf < -17.3f) break;        // 2^-17.3 ~ 6e-6
        const float4 Q1 = p1[n];
        const float4 Q2 = p2[n];
        float ph = P0.y * l0f;                 // phase in revolutions
        ph = __builtin_amdgcn_fractf(ph);
        const float s = __builtin_amdgcn_sinf(ph);   // sin(2*pi*ph)
        const float c = __builtin_amdgcn_cosf(ph);
        const float e = __builtin_amdgcn_exp2f(P0.x * l0f); // ->0 past cut
        const float kr = e * c;                // K(l0) = exp(dtA*l0)
        const float ki = e * s;
        // quad0: u_j = Re(Ej * K(l0))
        acc2[0] += v2f{Q1.x, Q1.y} * kr - v2f{Q1.z, Q1.w} * ki;
        acc2[1] += v2f{Q2.x, Q2.y} * kr - v2f{Q2.z, Q2.w} * ki;
        // quad1: K' = K * w^256
        const float k2r = kr * P0.z - ki * P0.w;
        const float k2i = kr * P0.w + ki * P0.z;
        acc2[2] += v2f{Q1.x, Q1.y} * k2r - v2f{Q1.z, Q1.w} * k2i;
        acc2[3] += v2f{Q2.x, Q2.y} * k2r - v2f{Q2.z, Q2.w} * k2i;
    }

    // Lane-contiguous float4 stores: each wave instruction covers 1024B
    // fully-written contiguous bytes (16 full cache lines).
    float4* outq = (float4*)(out + (size_t)h * LTOT + Lb);
    outq[lane]      = make_float4(acc2[0].x, acc2[0].y, acc2[1].x, acc2[1].y);
    outq[64 + lane] = make_float4(acc2[2].x, acc2[2].y, acc2[3].x, acc2[3].y);
}

extern "C" void kernel_launch(void* const* d_in, const int* in_sizes, int n_in,
                              void* d_out, int out_size, void* d_ws, size_t ws_size,
                              hipStream_t stream)
{
    (void)in_sizes; (void)n_in; (void)d_ws; (void)ws_size; (void)out_size;
    const float* log_dt     = (const float*)d_in[0];
    const float* log_A_real = (const float*)d_in[1];
    const float* A_imag     = (const float*)d_in[2];
    const float* Bmat       = (const float*)d_in[3];
    const float* Cmat       = (const float*)d_in[4];
    float* out = (float*)d_out;

    s4_kernel<<<dim3(HDIM * 4), dim3(TPB), 0, stream>>>(
        log_dt, log_A_real, A_imag, Bmat, Cmat, out);
}